// Round 1
// baseline (128.993 us; speedup 1.0000x reference)
//
#include <hip/hip_runtime.h>
#include <stdint.h>

#define UNITS 1024
#define BATCH 4096
#define FOURU 4096

typedef __bf16 bf16x8 __attribute__((ext_vector_type(8)));
typedef float f32x4 __attribute__((ext_vector_type(4)));

// round-to-nearest-even f32 -> bf16
__device__ __forceinline__ uint16_t f2bf(float f) {
  uint32_t u = __builtin_bit_cast(uint32_t, f);
  u += 0x7FFFu + ((u >> 16) & 1u);
  return (uint16_t)(u >> 16);
}

__device__ __forceinline__ float fsig(float x) {
  return 1.0f / (1.0f + __expf(-x));
}

__device__ __forceinline__ f32x4 mfma16x16x32(bf16x8 a, bf16x8 b, f32x4 c) {
  return __builtin_amdgcn_mfma_f32_16x16x32_bf16(a, b, c, 0, 0, 0);
}

// Stage a [rows x 32k] bf16 tile into LDS.
// Granule gi (16B = 8 bf16): row = gi>>2, kgroup = gi&3. Row-major [rows][32].
// Thread t handles granules {t, t+256, ...}. lda is always UNITS elems.
template <int NG>
__device__ __forceinline__ void stage_tile(const uint16_t* __restrict__ src,
                                           uint4* lds, int tid) {
#pragma unroll
  for (int p = 0; p < NG / 256; ++p) {
    int gi = p * 256 + tid;
    lds[gi] = *(const uint4*)(src + (gi >> 2) * UNITS + (gi & 3) * 8);
  }
}

// ---- prep: f32 -> bf16 convert (h_tm1) ----
__global__ __launch_bounds__(256) void convert_kernel(const float* __restrict__ in,
                                                      uint16_t* __restrict__ out) {
  const int i = (blockIdx.x * 256 + threadIdx.x) * 4;
  float4 v = *(const float4*)(in + i);
  ushort4 o;
  o.x = f2bf(v.x); o.y = f2bf(v.y); o.z = f2bf(v.z); o.w = f2bf(v.w);
  *(ushort4*)(out + i) = o;
}

// ---- prep: R (1024 x 4096, f32) -> RT (4096 x 1024, bf16) ----
__global__ __launch_bounds__(256) void transpose_kernel(const float* __restrict__ R,
                                                        uint16_t* __restrict__ RT) {
  __shared__ float t[32][33];
  const int n0 = blockIdx.x * 32, k0 = blockIdx.y * 32;
  const int tx = threadIdx.x & 31, ty = threadIdx.x >> 5;
#pragma unroll
  for (int i = 0; i < 4; ++i)
    t[ty + i * 8][tx] = R[(k0 + ty + i * 8) * FOURU + n0 + tx];
  __syncthreads();
#pragma unroll
  for (int i = 0; i < 4; ++i)
    RT[(n0 + ty + i * 8) * UNITS + k0 + tx] = f2bf(t[tx][ty + i * 8]);
}

// ---- stage 1: z,r gates. C1 = h @ [Rz|Rr]; z=sig(+cz+bz), r=sig(+cr+b0);
//      writes z (f32, stashed in o-region of d_out) and rh = bf16(r*h) ----
__global__ __launch_bounds__(256) void s1_kernel(
    const uint16_t* __restrict__ hbf, const uint16_t* __restrict__ rt,
    const int* __restrict__ idx, const float* __restrict__ kc,
    const float* __restrict__ bz, const float* __restrict__ bias,
    const float* __restrict__ h32, float* __restrict__ zbuf,
    uint16_t* __restrict__ rhb) {
  __shared__ uint4 sA[512], sBz[256], sBr[256];
  const int tid = threadIdx.x;
  const int lane = tid & 63, wave = tid >> 6;
  const int l15 = lane & 15, l4 = lane >> 4;
  const int row0 = blockIdx.y * 128, col0 = blockIdx.x * 64;
  const int rb = (wave >> 1) * 64, cb = (wave & 1) * 32;

  const uint16_t* pa = hbf + row0 * UNITS;
  const uint16_t* pbz = rt + col0 * UNITS;            // RT rows j        (gate z)
  const uint16_t* pbr = rt + (UNITS + col0) * UNITS;  // RT rows 1024+j   (gate r)

  f32x4 accZ[4][2] = {};
  f32x4 accR[4][2] = {};

  for (int k0 = 0; k0 < UNITS; k0 += 32) {
    stage_tile<512>(pa + k0, sA, tid);
    stage_tile<256>(pbz + k0, sBz, tid);
    stage_tile<256>(pbr + k0, sBr, tid);
    __syncthreads();
    const bf16x8* A8 = (const bf16x8*)sA;
    const bf16x8* Bz8 = (const bf16x8*)sBz;
    const bf16x8* Br8 = (const bf16x8*)sBr;
    bf16x8 af[4], bzf[2], brf[2];
#pragma unroll
    for (int m = 0; m < 4; ++m) af[m] = A8[(rb + m * 16 + l15) * 4 + l4];
#pragma unroll
    for (int n = 0; n < 2; ++n) {
      bzf[n] = Bz8[(cb + n * 16 + l15) * 4 + l4];
      brf[n] = Br8[(cb + n * 16 + l15) * 4 + l4];
    }
#pragma unroll
    for (int m = 0; m < 4; ++m)
#pragma unroll
      for (int n = 0; n < 2; ++n) {
        accZ[m][n] = mfma16x16x32(af[m], bzf[n], accZ[m][n]);
        accR[m][n] = mfma16x16x32(af[m], brf[n], accR[m][n]);
      }
    __syncthreads();
  }

#pragma unroll
  for (int m = 0; m < 4; ++m) {
#pragma unroll
    for (int q = 0; q < 4; ++q) {
      const int i = row0 + rb + m * 16 + l4 * 4 + q;
      const int ch = idx[i];
      const float* kcrow = kc + ch * FOURU;
#pragma unroll
      for (int n = 0; n < 2; ++n) {
        const int j = col0 + cb + n * 16 + l15;
        const int ij = i * UNITS + j;
        float z = fsig(accZ[m][n][q] + kcrow[j] + bz[j]);
        float r = fsig(accR[m][n][q] + kcrow[UNITS + j] + bias[j]);
        float hv = h32[ij];
        zbuf[ij] = z;
        rhb[ij] = f2bf(r * hv);
      }
    }
  }
}

// ---- stage 2 (MODE 0): hh = tanh((r*h)@Rh + ch + b1); hn = z*h+(1-z)*hh
//      stage 3 (MODE 1): o  = tanh(hn@Ro + co + b2) ----
template <int MODE>
__global__ __launch_bounds__(256) void s23_kernel(
    const uint16_t* __restrict__ abf, const uint16_t* __restrict__ bt,
    const int* __restrict__ idx, const float* __restrict__ kc,
    const float* __restrict__ bias, const float* __restrict__ h32,
    const float* __restrict__ zbuf, float* __restrict__ out32,
    uint16_t* __restrict__ outbf) {
  __shared__ uint4 sA[512], sB[256];
  const int tid = threadIdx.x;
  const int lane = tid & 63, wave = tid >> 6;
  const int l15 = lane & 15, l4 = lane >> 4;
  const int row0 = blockIdx.y * 128, col0 = blockIdx.x * 64;
  const int rb = (wave >> 1) * 64, cb = (wave & 1) * 32;
  const uint16_t* pa = abf + row0 * UNITS;
  const uint16_t* pb = bt + col0 * UNITS;
  f32x4 acc[4][2] = {};

  for (int k0 = 0; k0 < UNITS; k0 += 32) {
    stage_tile<512>(pa + k0, sA, tid);
    stage_tile<256>(pb + k0, sB, tid);
    __syncthreads();
    const bf16x8* A8 = (const bf16x8*)sA;
    const bf16x8* B8 = (const bf16x8*)sB;
    bf16x8 af[4], bff[2];
#pragma unroll
    for (int m = 0; m < 4; ++m) af[m] = A8[(rb + m * 16 + l15) * 4 + l4];
#pragma unroll
    for (int n = 0; n < 2; ++n) bff[n] = B8[(cb + n * 16 + l15) * 4 + l4];
#pragma unroll
    for (int m = 0; m < 4; ++m)
#pragma unroll
      for (int n = 0; n < 2; ++n)
        acc[m][n] = mfma16x16x32(af[m], bff[n], acc[m][n]);
    __syncthreads();
  }

#pragma unroll
  for (int m = 0; m < 4; ++m) {
#pragma unroll
    for (int q = 0; q < 4; ++q) {
      const int i = row0 + rb + m * 16 + l4 * 4 + q;
      const int ch = idx[i];
      const float* kcrow = kc + ch * FOURU;
#pragma unroll
      for (int n = 0; n < 2; ++n) {
        const int j = col0 + cb + n * 16 + l15;
        const int ij = i * UNITS + j;
        if (MODE == 0) {
          float hh = tanhf(acc[m][n][q] + kcrow[2 * UNITS + j] + bias[UNITS + j]);
          float z = zbuf[ij];
          float hv = h32[ij];
          float hn = z * hv + (1.0f - z) * hh;
          out32[ij] = hn;
          outbf[ij] = f2bf(hn);
        } else {
          float o = tanhf(acc[m][n][q] + kcrow[3 * UNITS + j] + bias[2 * UNITS + j]);
          out32[ij] = o;
        }
      }
    }
  }
}

extern "C" void kernel_launch(void* const* d_in, const int* in_sizes, int n_in,
                              void* d_out, int out_size, void* d_ws, size_t ws_size,
                              hipStream_t stream) {
  const int* idx = (const int*)d_in[0];
  const float* h32 = (const float*)d_in[1];
  const float* R = (const float*)d_in[2];
  const float* kc = (const float*)d_in[3];
  const float* bz = (const float*)d_in[4];
  const float* bias = (const float*)d_in[5];

  float* o_out = (float*)d_out;                       // 4M f32 (output o)
  float* h_out = o_out + (size_t)BATCH * UNITS;       // 4M f32 (output h)

  uint16_t* hbf = (uint16_t*)d_ws;                    // bf16(h_tm1)      8 MB
  uint16_t* rt = hbf + (size_t)BATCH * UNITS;         // bf16(R^T) 4096x1024, 8 MB
  uint16_t* rhb = rt + (size_t)FOURU * UNITS;         // bf16(r*h)        8 MB
  uint16_t* hnb = rhb + (size_t)BATCH * UNITS;        // bf16(h_new)      8 MB
  float* zbuf = o_out;  // stash z in o-region; consumed by stage 2, overwritten by stage 3

  convert_kernel<<<dim3(BATCH * UNITS / 1024), 256, 0, stream>>>(h32, hbf);
  transpose_kernel<<<dim3(FOURU / 32, UNITS / 32), 256, 0, stream>>>(R, rt);
  s1_kernel<<<dim3(UNITS / 64, BATCH / 128), 256, 0, stream>>>(
      hbf, rt, idx, kc, bz, bias, h32, zbuf, rhb);
  s23_kernel<0><<<dim3(UNITS / 64, BATCH / 128), 256, 0, stream>>>(
      rhb, rt + (size_t)2 * UNITS * UNITS, idx, kc, bias, h32, zbuf, h_out, hnb);
  s23_kernel<1><<<dim3(UNITS / 64, BATCH / 128), 256, 0, stream>>>(
      hnb, rt + (size_t)3 * UNITS * UNITS, idx, kc, bias, nullptr, nullptr, o_out, nullptr);
}

// Round 2
// 121.340 us; speedup vs baseline: 1.0631x; 1.0631x over previous
//
#include <hip/hip_runtime.h>
#include <stdint.h>

#define UNITS 1024
#define BATCH 4096
#define FOURU 4096

typedef __bf16 bf16x8 __attribute__((ext_vector_type(8)));
typedef float f32x4 __attribute__((ext_vector_type(4)));

// round-to-nearest-even f32 -> bf16
__device__ __forceinline__ uint16_t f2bf(float f) {
  uint32_t u = __builtin_bit_cast(uint32_t, f);
  u += 0x7FFFu + ((u >> 16) & 1u);
  return (uint16_t)(u >> 16);
}
__device__ __forceinline__ float bf2f(uint16_t b) {
  uint32_t u = ((uint32_t)b) << 16;
  return __builtin_bit_cast(float, u);
}
__device__ __forceinline__ float fsig(float x) {
  return 1.0f / (1.0f + __expf(-x));
}
__device__ __forceinline__ f32x4 mfma16x16x32(bf16x8 a, bf16x8 b, f32x4 c) {
  return __builtin_amdgcn_mfma_f32_16x16x32_bf16(a, b, c, 0, 0, 0);
}

// async global->LDS, 16B per lane; LDS dest is wave-uniform base + lane*16
__device__ __forceinline__ void gll16(uint16_t* lds, const uint16_t* g) {
  __builtin_amdgcn_global_load_lds(
      (const __attribute__((address_space(1))) uint32_t*)g,
      (__attribute__((address_space(3))) uint32_t*)lds, 16, 0, 0);
}

// Stage a [rows x 32k] bf16 tile (row-major [rows][32]) into LDS via
// global_load_lds. Granule gi (16B): row = gi>>2, kgroup = gi&3.
// Lane layout is linear in gi, so dest = wavebase + lane*16 matches.
template <int NG>
__device__ __forceinline__ void stage(const uint16_t* __restrict__ src,
                                      uint16_t* lds, int tid) {
  const int wb = tid & 192;  // wave*64
#pragma unroll
  for (int p = 0; p < NG / 256; ++p) {
    const int gi = p * 256 + tid;
    gll16(lds + (p * 256 + wb) * 8, src + (gi >> 2) * UNITS + (gi & 3) * 8);
  }
}

// ---- prep: f32 -> bf16 convert (h_tm1) ----
__global__ __launch_bounds__(256) void convert_kernel(const float* __restrict__ in,
                                                      uint16_t* __restrict__ out) {
  const int i = (blockIdx.x * 256 + threadIdx.x) * 4;
  float4 v = *(const float4*)(in + i);
  ushort4 o;
  o.x = f2bf(v.x); o.y = f2bf(v.y); o.z = f2bf(v.z); o.w = f2bf(v.w);
  *(ushort4*)(out + i) = o;
}

// ---- prep: R (1024 x 4096, f32) -> RT (4096 x 1024, bf16) ----
__global__ __launch_bounds__(256) void transpose_kernel(const float* __restrict__ R,
                                                        uint16_t* __restrict__ RT) {
  __shared__ float t[32][33];
  const int n0 = blockIdx.x * 32, k0 = blockIdx.y * 32;
  const int tx = threadIdx.x & 31, ty = threadIdx.x >> 5;
#pragma unroll
  for (int i = 0; i < 4; ++i)
    t[ty + i * 8][tx] = R[(k0 + ty + i * 8) * FOURU + n0 + tx];
  __syncthreads();
#pragma unroll
  for (int i = 0; i < 4; ++i)
    RT[(n0 + ty + i * 8) * UNITS + k0 + tx] = f2bf(t[tx][ty + i * 8]);
}

// ---- stage 1: z,r gates. Dual-tile GEMM C = h @ [Rz | Rr];
//      z=sig(+cz+bz) -> zb (bf16), rh = bf16(r*h) -> rhb ----
__global__ __launch_bounds__(256) void s1_kernel(
    const uint16_t* __restrict__ hbf, const uint16_t* __restrict__ rt,
    const int* __restrict__ idx, const float* __restrict__ kc,
    const float* __restrict__ bz, const float* __restrict__ bias,
    uint16_t* __restrict__ zb, uint16_t* __restrict__ rhb) {
  __shared__ uint16_t sA[2][512 * 8];   // 128 x 32 per buf
  __shared__ uint16_t sBz[2][256 * 8];  // 64 x 32 per buf
  __shared__ uint16_t sBr[2][256 * 8];
  const int tid = threadIdx.x;
  const int lane = tid & 63, wave = tid >> 6;
  const int l15 = lane & 15, l4 = lane >> 4;
  const int row0 = blockIdx.y * 128, col0 = blockIdx.x * 64;
  const int rb = (wave >> 1) * 64, cb = (wave & 1) * 32;

  const uint16_t* pa = hbf + row0 * UNITS;
  const uint16_t* pbz = rt + col0 * UNITS;            // RT rows j       (gate z)
  const uint16_t* pbr = rt + (UNITS + col0) * UNITS;  // RT rows 1024+j  (gate r)

  f32x4 accZ[4][2] = {};
  f32x4 accR[4][2] = {};

  // prologue: stage tile 0
  stage<512>(pa, sA[0], tid);
  stage<256>(pbz, sBz[0], tid);
  stage<256>(pbr, sBr[0], tid);
  __syncthreads();

  int cur = 0;
  for (int k0 = 0; k0 < UNITS; k0 += 32) {
    if (k0 + 32 < UNITS) {  // issue next-tile loads before compute
      stage<512>(pa + k0 + 32, sA[cur ^ 1], tid);
      stage<256>(pbz + k0 + 32, sBz[cur ^ 1], tid);
      stage<256>(pbr + k0 + 32, sBr[cur ^ 1], tid);
    }
    const bf16x8* A8 = (const bf16x8*)sA[cur];
    const bf16x8* Bz8 = (const bf16x8*)sBz[cur];
    const bf16x8* Br8 = (const bf16x8*)sBr[cur];
    bf16x8 af[4], bzf[2], brf[2];
#pragma unroll
    for (int m = 0; m < 4; ++m) af[m] = A8[(rb + m * 16 + l15) * 4 + l4];
#pragma unroll
    for (int n = 0; n < 2; ++n) {
      bzf[n] = Bz8[(cb + n * 16 + l15) * 4 + l4];
      brf[n] = Br8[(cb + n * 16 + l15) * 4 + l4];
    }
#pragma unroll
    for (int m = 0; m < 4; ++m)
#pragma unroll
      for (int n = 0; n < 2; ++n) {
        accZ[m][n] = mfma16x16x32(af[m], bzf[n], accZ[m][n]);
        accR[m][n] = mfma16x16x32(af[m], brf[n], accR[m][n]);
      }
    __syncthreads();  // drains next-tile global_load_lds + read-done fence
    cur ^= 1;
  }

#pragma unroll
  for (int m = 0; m < 4; ++m) {
#pragma unroll
    for (int q = 0; q < 4; ++q) {
      const int i = row0 + rb + m * 16 + l4 * 4 + q;
      const int ch = idx[i];
      const float* kcrow = kc + ch * FOURU;
#pragma unroll
      for (int n = 0; n < 2; ++n) {
        const int j = col0 + cb + n * 16 + l15;
        const int ij = i * UNITS + j;
        float z = fsig(accZ[m][n][q] + kcrow[j] + bz[j]);
        float r = fsig(accR[m][n][q] + kcrow[UNITS + j] + bias[j]);
        float hv = bf2f(hbf[ij]);  // product is rounded to bf16 anyway
        zb[ij] = f2bf(z);
        rhb[ij] = f2bf(r * hv);
      }
    }
  }
}

// ---- stage 2 (MODE 0): hh = tanh((r*h)@Rh + ch + b1); hn = z*h+(1-z)*hh
//      stage 3 (MODE 1): o  = tanh(hn@Ro + co + b2) ----
template <int MODE>
__global__ __launch_bounds__(256) void s23_kernel(
    const uint16_t* __restrict__ abf, const uint16_t* __restrict__ bt,
    const int* __restrict__ idx, const float* __restrict__ kc,
    const float* __restrict__ bias, const float* __restrict__ h32,
    const uint16_t* __restrict__ zb, float* __restrict__ out32,
    uint16_t* __restrict__ outbf) {
  __shared__ uint16_t sA[2][512 * 8];
  __shared__ uint16_t sB[2][256 * 8];
  const int tid = threadIdx.x;
  const int lane = tid & 63, wave = tid >> 6;
  const int l15 = lane & 15, l4 = lane >> 4;
  const int row0 = blockIdx.y * 128, col0 = blockIdx.x * 64;
  const int rb = (wave >> 1) * 64, cb = (wave & 1) * 32;
  const uint16_t* pa = abf + row0 * UNITS;
  const uint16_t* pb = bt + col0 * UNITS;
  f32x4 acc[4][2] = {};

  stage<512>(pa, sA[0], tid);
  stage<256>(pb, sB[0], tid);
  __syncthreads();

  int cur = 0;
  for (int k0 = 0; k0 < UNITS; k0 += 32) {
    if (k0 + 32 < UNITS) {
      stage<512>(pa + k0 + 32, sA[cur ^ 1], tid);
      stage<256>(pb + k0 + 32, sB[cur ^ 1], tid);
    }
    const bf16x8* A8 = (const bf16x8*)sA[cur];
    const bf16x8* B8 = (const bf16x8*)sB[cur];
    bf16x8 af[4], bff[2];
#pragma unroll
    for (int m = 0; m < 4; ++m) af[m] = A8[(rb + m * 16 + l15) * 4 + l4];
#pragma unroll
    for (int n = 0; n < 2; ++n) bff[n] = B8[(cb + n * 16 + l15) * 4 + l4];
#pragma unroll
    for (int m = 0; m < 4; ++m)
#pragma unroll
      for (int n = 0; n < 2; ++n)
        acc[m][n] = mfma16x16x32(af[m], bff[n], acc[m][n]);
    __syncthreads();
    cur ^= 1;
  }

#pragma unroll
  for (int m = 0; m < 4; ++m) {
#pragma unroll
    for (int q = 0; q < 4; ++q) {
      const int i = row0 + rb + m * 16 + l4 * 4 + q;
      const int ch = idx[i];
      const float* kcrow = kc + ch * FOURU;
#pragma unroll
      for (int n = 0; n < 2; ++n) {
        const int j = col0 + cb + n * 16 + l15;
        const int ij = i * UNITS + j;
        if (MODE == 0) {
          float hh = tanhf(acc[m][n][q] + kcrow[2 * UNITS + j] + bias[UNITS + j]);
          float z = bf2f(zb[ij]);
          float hv = h32[ij];
          float hn = z * hv + (1.0f - z) * hh;
          out32[ij] = hn;
          outbf[ij] = f2bf(hn);
        } else {
          float o = tanhf(acc[m][n][q] + kcrow[3 * UNITS + j] + bias[2 * UNITS + j]);
          out32[ij] = o;
        }
      }
    }
  }
}

extern "C" void kernel_launch(void* const* d_in, const int* in_sizes, int n_in,
                              void* d_out, int out_size, void* d_ws, size_t ws_size,
                              hipStream_t stream) {
  const int* idx = (const int*)d_in[0];
  const float* h32 = (const float*)d_in[1];
  const float* R = (const float*)d_in[2];
  const float* kc = (const float*)d_in[3];
  const float* bz = (const float*)d_in[4];
  const float* bias = (const float*)d_in[5];

  float* o_out = (float*)d_out;                  // 4M f32 (output o)
  float* h_out = o_out + (size_t)BATCH * UNITS;  // 4M f32 (output h)

  uint16_t* hbf = (uint16_t*)d_ws;                 // bf16(h_tm1)       8 MB
  uint16_t* rt = hbf + (size_t)BATCH * UNITS;      // bf16(R^T)         8 MB
  uint16_t* rhb = rt + (size_t)FOURU * UNITS;      // bf16(r*h)         8 MB
  uint16_t* hnb = rhb + (size_t)BATCH * UNITS;     // bf16(h_new)       8 MB
  uint16_t* zbuf = hnb + (size_t)BATCH * UNITS;    // bf16(z)           8 MB

  convert_kernel<<<dim3(BATCH * UNITS / 1024), 256, 0, stream>>>(h32, hbf);
  transpose_kernel<<<dim3(FOURU / 32, UNITS / 32), 256, 0, stream>>>(R, rt);
  s1_kernel<<<dim3(UNITS / 64, BATCH / 128), 256, 0, stream>>>(
      hbf, rt, idx, kc, bz, bias, zbuf, rhb);
  s23_kernel<0><<<dim3(UNITS / 64, BATCH / 128), 256, 0, stream>>>(
      rhb, rt + (size_t)2 * UNITS * UNITS, idx, kc, bias, h32, zbuf, h_out, hnb);
  s23_kernel<1><<<dim3(UNITS / 64, BATCH / 128), 256, 0, stream>>>(
      hnb, rt + (size_t)3 * UNITS * UNITS, idx, kc, bias, nullptr, nullptr, o_out, nullptr);
}